// Round 1
// baseline (157.442 us; speedup 1.0000x reference)
//
#include <hip/hip_runtime.h>

#define B_ 2
#define T_ 2048
#define C_ 1024
#define H_ 16
#define HD_ 64

typedef unsigned short u16;
typedef unsigned int u32;
typedef __attribute__((ext_vector_type(8))) short short8;
typedef __attribute__((ext_vector_type(4))) float f32x4;
typedef __attribute__((ext_vector_type(2))) u32 uint2v;

typedef __attribute__((address_space(1))) const void* as1cv;
typedef __attribute__((address_space(3))) void* as3v;

__device__ __forceinline__ u16 f2bf(float x){
  union { float f; u32 u; } v; v.f = x;
  u32 r = v.u + 0x7fffu + ((v.u >> 16) & 1u);
  return (u16)(r >> 16);
}
__device__ __forceinline__ float bf2f(u16 h){
  union { u32 u; float f; } v; v.u = ((u32)h) << 16;
  return v.f;
}
__device__ __forceinline__ void gl_lds16(const u16* src, u16* dst){
  __builtin_amdgcn_global_load_lds((as1cv)src, (as3v)dst, 16, 0, 0);
}

// ---------------- f32 -> bf16 convert (x4 vectorized) ----------------
__global__ void k_conv(const float* __restrict__ in, u16* __restrict__ out){
  int i = blockIdx.x * 256 + threadIdx.x;
  f32x4 v = ((const f32x4*)in)[i];
  uint2v o;
  o.x = (u32)f2bf(v.x) | ((u32)f2bf(v.y) << 16);
  o.y = (u32)f2bf(v.z) | ((u32)f2bf(v.w) << 16);
  ((uint2v*)out)[i] = o;
}

// ------------- transpose + convert: out[c][r] = bf16(in[r][c]) -------------
__global__ void k_transpose(const float* __restrict__ in, u16* __restrict__ out,
                            int R, int Cc){
  __shared__ float tile[32][33];
  int c0 = blockIdx.x * 32, r0 = blockIdx.y * 32;
  int tx = threadIdx.x, ty = threadIdx.y;
#pragma unroll
  for (int ii = 0; ii < 4; ++ii)
    tile[ty + ii*8][tx] = in[(size_t)(r0 + ty + ii*8) * Cc + c0 + tx];
  __syncthreads();
#pragma unroll
  for (int ii = 0; ii < 4; ++ii)
    out[(size_t)(c0 + ty + ii*8) * R + r0 + tx] = f2bf(tile[tx][ty + ii*8]);
}

// ---------------- GEMM: C = A[MxK] * Bt[NxK]^T + bias ----------------
// MODE 0: bf16 out to qkv (cols<2048) + transposed V to vt (cols>=2048)
// MODE 1: f32 out + bias
template<int MODE>
__global__ __launch_bounds__(256, 2)
void k_gemm(const u16* __restrict__ A, const u16* __restrict__ Bt,
            const float* __restrict__ bias, u16* __restrict__ outb,
            float* __restrict__ outf, u16* __restrict__ vt,
            int M, int N, int K)
{
  __shared__ u16 As[128*64];
  __shared__ u16 Bs[128*64];
  int nwg = gridDim.x;
  int cpx = nwg >> 3;                      // nwg % 8 == 0 guaranteed by launch
  int bid = blockIdx.x;
  int wg = (bid & 7) * cpx + (bid >> 3);   // bijective XCD swizzle
  int ntn = N >> 7;
  int m0 = (wg / ntn) << 7, n0 = (wg % ntn) << 7;
  int tid = threadIdx.x;
  int lane = tid & 63, w = tid >> 6;
  int c = lane & 15, g = lane >> 4;
  int wr = w >> 1, wc = w & 1;

  f32x4 z4 = {0.f,0.f,0.f,0.f};
  f32x4 acc[4][4];
#pragma unroll
  for (int i=0;i<4;++i)
#pragma unroll
    for (int j=0;j<4;++j) acc[i][j] = z4;

  u16* dstA = As + ((tid & 0xC0) << 3);    // wave-uniform LDS base
  u16* dstB = Bs + ((tid & 0xC0) << 3);

  for (int k0 = 0; k0 < K; k0 += 64){
#pragma unroll
    for (int it = 0; it < 4; ++it){
      int ch = it*256 + tid;
      int row = ch >> 3, slot = ch & 7;
      gl_lds16(A + (size_t)(m0+row)*K + k0 + slot*8, dstA + it*2048);
    }
#pragma unroll
    for (int it = 0; it < 4; ++it){
      int ch = it*256 + tid;
      int row = ch >> 3, slot = ch & 7;
      gl_lds16(Bt + (size_t)(n0+row)*K + k0 + slot*8, dstB + it*2048);
    }
    __syncthreads();
#pragma unroll
    for (int ks = 0; ks < 2; ++ks){
      short8 af[4], bf[4];
#pragma unroll
      for (int i=0;i<4;++i)
        af[i] = *(const short8*)(As + (wr*64 + i*16 + c)*64 + ks*32 + g*8);
#pragma unroll
      for (int j=0;j<4;++j)
        bf[j] = *(const short8*)(Bs + (wc*64 + j*16 + c)*64 + ks*32 + g*8);
#pragma unroll
      for (int i=0;i<4;++i)
#pragma unroll
        for (int j=0;j<4;++j)
          acc[i][j] = __builtin_amdgcn_mfma_f32_16x16x32_bf16(af[i], bf[j], acc[i][j], 0, 0, 0);
    }
    __syncthreads();
  }

  if (MODE == 0){
    if (n0 >= 2048){
      // V section -> vt[bh][d][t], 4 consecutive t packed per 8B store
#pragma unroll
      for (int i=0;i<4;++i){
        int rowb = m0 + wr*64 + i*16 + g*4;
        int bb = rowb >> 11, t0 = rowb & 2047;
#pragma unroll
        for (int j=0;j<4;++j){
          int col = n0 + wc*64 + j*16 + c;
          float bv = bias[col];
          int vc = col - 2048;
          int hh = vc >> 6, d = vc & 63;
          uint2v o;
          o.x = (u32)f2bf(acc[i][j].x + bv) | ((u32)f2bf(acc[i][j].y + bv) << 16);
          o.y = (u32)f2bf(acc[i][j].z + bv) | ((u32)f2bf(acc[i][j].w + bv) << 16);
          *(uint2v*)(vt + ((size_t)((bb*16 + hh)*64 + d))*2048 + t0) = o;
        }
      }
    } else {
#pragma unroll
      for (int i=0;i<4;++i){
#pragma unroll
        for (int j=0;j<4;++j){
          int col = n0 + wc*64 + j*16 + c;
          float bv = bias[col];
#pragma unroll
          for (int r=0;r<4;++r){
            int row = m0 + wr*64 + i*16 + g*4 + r;
            outb[(size_t)row*3072 + col] = f2bf(acc[i][j][r] + bv);
          }
        }
      }
    }
  } else {
#pragma unroll
    for (int i=0;i<4;++i){
#pragma unroll
      for (int j=0;j<4;++j){
        int col = n0 + wc*64 + j*16 + c;
        float bv = bias[col];
#pragma unroll
        for (int r=0;r<4;++r){
          int row = m0 + wr*64 + i*16 + g*4 + r;
          outf[(size_t)row*N + col] = acc[i][j][r] + bv;
        }
      }
    }
  }
}

// ---------------- RoPE + head split (q scaled by 1/8) ----------------
__global__ void k_rope(const u16* __restrict__ qkv, u16* __restrict__ Qh,
                       u16* __restrict__ Kh){
  int idx = blockIdx.x * 256 + threadIdx.x;   // 0 .. 4M-1
  int sec = idx >> 21;                        // 0 = q, 1 = k
  int p = idx & 0x1FFFFF;
  int row = p >> 9;                           // b*T + t
  int ii = p & 511;
  int h = ii >> 5, ip = ii & 31;
  int t = row & 2047;
  int b = row >> 11;
  // inv_freq = 10000^(-2*ip/64) = exp2(-(2*ip/64)*log2(10000))
  float invf = exp2f((float)(-2 * ip) * (1.f/64.f) * 13.287712379549449f);
  float th = (float)t * invf;
  float sn, cs;
  sincosf(th, &sn, &cs);
  u32 v = *(const u32*)(qkv + (size_t)row*3072 + sec*1024 + h*64 + 2*ip);
  float x0 = bf2f((u16)(v & 0xFFFFu));
  float x1 = bf2f((u16)(v >> 16));
  float y0 = x0*cs - x1*sn;
  float y1 = x1*cs + x0*sn;
  if (sec == 0){ y0 *= 0.125f; y1 *= 0.125f; }
  u32 o = (u32)f2bf(y0) | ((u32)f2bf(y1) << 16);
  u16* dst = sec ? Kh : Qh;
  *(u32*)(dst + ((size_t)((b*16 + h)*2048 + t))*64 + 2*ip) = o;
}

// ---------------- causal flash attention ----------------
// Qh,Kh: [bh][t][64] bf16 (Q pre-scaled).  Vt: [bh][64][t] bf16.  Y: [b*T][1024] bf16
__global__ __launch_bounds__(256, 2)
void k_attn(const u16* __restrict__ Qh, const u16* __restrict__ Kh,
            const u16* __restrict__ Vt, u16* __restrict__ Y)
{
  __shared__ u16 Ks[64*64];      // [kv][d], XOR-swizzled 16B chunks
  __shared__ u16 Vs[64*64];      // V^T [d][kv], XOR-swizzled
  __shared__ u16 Ps[4*32*64];    // per-wave P[q][kv], XOR-swizzled

  int qt = blockIdx.x, bh = blockIdx.y;
  int b = bh >> 4, h = bh & 15;
  int q0 = qt << 7;
  int tid = threadIdx.x, lane = tid & 63, w = tid >> 6;
  int c = lane & 15, g = lane >> 4;
  int q0w = q0 + w*32;

  const u16* Kbase = Kh + (size_t)bh * T_ * 64;
  const u16* Vbase = Vt + (size_t)bh * 64 * T_;
  const u16* Qbase = Qh + (size_t)bh * T_ * 64;

  short8 qf[2][2];
#pragma unroll
  for (int qs=0;qs<2;++qs)
#pragma unroll
    for (int ks=0;ks<2;++ks)
      qf[qs][ks] = *(const short8*)(Qbase + (size_t)(q0w + qs*16 + c)*64 + ks*32 + g*8);

  f32x4 z4 = {0.f,0.f,0.f,0.f};
  f32x4 acc[2][4];
#pragma unroll
  for (int qs=0;qs<2;++qs)
#pragma unroll
    for (int ds=0;ds<4;++ds) acc[qs][ds] = z4;
  float m[2] = {-INFINITY, -INFINITY};
  float lsum[2] = {0.f, 0.f};

  char* PsB = (char*)Ps + w*4096;

  for (int kv0 = 0; kv0 < q0 + 128; kv0 += 64){
    // stage K rows and V^T rows; swizzle via pre-swizzled global source
#pragma unroll
    for (int it=0; it<2; ++it){
      int ch = it*256 + tid;
      int row = ch >> 3, slot = ch & 7;
      gl_lds16(Kbase + (size_t)(kv0 + row)*64 + ((slot ^ (row & 7)) << 3),
               Ks + ((it*256 + (tid & 0xC0)) << 3));
    }
#pragma unroll
    for (int it=0; it<2; ++it){
      int ch = it*256 + tid;
      int row = ch >> 3, slot = ch & 7;
      gl_lds16(Vbase + (size_t)row*T_ + kv0 + ((slot ^ (row & 7)) << 3),
               Vs + ((it*256 + (tid & 0xC0)) << 3));
    }
    __syncthreads();

    if (kv0 <= q0w + 31){   // wave-uniform: this wave has unmasked work
      // S^T = K * Q^T  ->  lane holds kv=(16*kv + 4g + r), q=(16*qs + c)
      f32x4 st[4][2];
#pragma unroll
      for (int kv=0;kv<4;++kv)
#pragma unroll
        for (int qs=0;qs<2;++qs) st[kv][qs] = z4;

#pragma unroll
      for (int ks=0;ks<2;++ks){
        short8 kf[4];
#pragma unroll
        for (int kv=0;kv<4;++kv){
          int row = kv*16 + c;
          kf[kv] = *(const short8*)((const char*)Ks + row*128 + (((ks*4+g) ^ (row&7)) << 4));
        }
#pragma unroll
        for (int kv=0;kv<4;++kv)
#pragma unroll
          for (int qs=0;qs<2;++qs)
            st[kv][qs] = __builtin_amdgcn_mfma_f32_16x16x32_bf16(kf[kv], qf[qs][ks], st[kv][qs], 0, 0, 0);
      }

      if (kv0 + 63 > q0w){  // diagonal tile: causal mask
#pragma unroll
        for (int kv=0;kv<4;++kv)
#pragma unroll
          for (int qs=0;qs<2;++qs)
#pragma unroll
            for (int r=0;r<4;++r){
              int kvi = kv0 + kv*16 + g*4 + r;
              int qi = q0w + qs*16 + c;
              if (kvi > qi) st[kv][qs][r] = -INFINITY;
            }
      }

#pragma unroll
      for (int qs=0;qs<2;++qs){
        float pm = -INFINITY;
#pragma unroll
        for (int kv=0;kv<4;++kv)
#pragma unroll
          for (int r=0;r<4;++r) pm = fmaxf(pm, st[kv][qs][r]);
        pm = fmaxf(pm, __shfl_xor(pm, 16));
        pm = fmaxf(pm, __shfl_xor(pm, 32));
        float mnew = fmaxf(m[qs], pm);
        float fac = __expf(m[qs] - mnew);
        float ts = 0.f;
#pragma unroll
        for (int kv=0;kv<4;++kv)
#pragma unroll
          for (int r=0;r<4;++r){
            float pv = __expf(st[kv][qs][r] - mnew);
            st[kv][qs][r] = pv;
            ts += pv;
          }
        ts += __shfl_xor(ts, 16);
        ts += __shfl_xor(ts, 32);
        lsum[qs] = lsum[qs]*fac + ts;
        m[qs] = mnew;
        // rescale O rows (rows live at q = 16*qs + 4g + r -> fetch fac from lane 4g+r)
#pragma unroll
        for (int r=0;r<4;++r){
          float fr = __shfl(fac, g*4 + r);
#pragma unroll
          for (int ds=0;ds<4;++ds) acc[qs][ds][r] *= fr;
        }
        // write P[q][kv]: 4 consecutive kv per lane -> packed 8B, swizzled
        int q = qs*16 + c;
#pragma unroll
        for (int kv=0;kv<4;++kv){
          uint2v o;
          o.x = (u32)f2bf(st[kv][qs][0]) | ((u32)f2bf(st[kv][qs][1]) << 16);
          o.y = (u32)f2bf(st[kv][qs][2]) | ((u32)f2bf(st[kv][qs][3]) << 16);
          *(uint2v*)(PsB + q*128 + ((kv*32 + g*8) ^ ((q&7) << 4))) = o;
        }
      }

      // O += P * V   (A = P from Ps, B = V from Vs = V^T rows)
#pragma unroll
      for (int ks=0;ks<2;++ks){
        short8 vb[4];
#pragma unroll
        for (int ds=0;ds<4;++ds){
          int row = ds*16 + c;
          vb[ds] = *(const short8*)((const char*)Vs + row*128 + (((ks*4+g) ^ (row&7)) << 4));
        }
#pragma unroll
        for (int qs=0;qs<2;++qs){
          int q = qs*16 + c;
          short8 pa = *(const short8*)(PsB + q*128 + (((ks*4+g) << 4) ^ ((q&7) << 4)));
#pragma unroll
          for (int ds=0;ds<4;++ds)
            acc[qs][ds] = __builtin_amdgcn_mfma_f32_16x16x32_bf16(pa, vb[ds], acc[qs][ds], 0, 0, 0);
        }
      }
    }
    __syncthreads();
  }

  // epilogue: divide by lsum (per-row, fetched cross-lane), write Y
#pragma unroll
  for (int qs=0;qs<2;++qs){
#pragma unroll
    for (int r=0;r<4;++r){
      float lr = __shfl(lsum[qs], g*4 + r);
      float inv = 1.0f / lr;
      int trow = q0w + qs*16 + g*4 + r;
      size_t yoff = ((size_t)(b*2048 + trow))*1024 + (size_t)h*64;
#pragma unroll
      for (int ds=0;ds<4;++ds)
        Y[yoff + ds*16 + c] = f2bf(acc[qs][ds][r] * inv);
    }
  }
}

extern "C" void kernel_launch(void* const* d_in, const int* in_sizes, int n_in,
                              void* d_out, int out_size, void* d_ws, size_t ws_size,
                              hipStream_t stream)
{
  const float* x  = (const float*)d_in[0];
  const float* Wa = (const float*)d_in[1];
  const float* ba = (const float*)d_in[2];
  const float* Wp = (const float*)d_in[3];
  const float* bp = (const float*)d_in[4];
  float* out = (float*)d_out;
  char* ws = (char*)d_ws;

  // workspace layout (64 MB total)
  u16* xb  = (u16*)(ws);                    //  8 MB  x bf16 [4096][1024]
  u16* WaT = (u16*)(ws + (8u  << 20));      //  6 MB  W_attn^T bf16 [3072][1024]
  u16* WpT = (u16*)(ws + (14u << 20));      //  2 MB  W_proj^T bf16 [1024][1024]
  u16* qkv = (u16*)(ws + (16u << 20));      // 24 MB  qkv bf16 [4096][3072] (v cols unused)
  u16* Y   = qkv;                           //  8 MB  attn out (reuses qkv region)
  u16* Qh  = (u16*)(ws + (40u << 20));      //  8 MB  [32][2048][64]
  u16* Kh  = (u16*)(ws + (48u << 20));      //  8 MB  [32][2048][64]
  u16* Vt  = (u16*)(ws + (56u << 20));      //  8 MB  [32][64][2048]

  k_conv<<<4096, 256, 0, stream>>>(x, xb);
  k_transpose<<<dim3(96,32), dim3(32,8), 0, stream>>>(Wa, WaT, 1024, 3072);
  k_transpose<<<dim3(32,32), dim3(32,8), 0, stream>>>(Wp, WpT, 1024, 1024);
  k_gemm<0><<<768, 256, 0, stream>>>(xb, WaT, ba, qkv, nullptr, Vt, 4096, 3072, 1024);
  k_rope<<<16384, 256, 0, stream>>>(qkv, Qh, Kh);
  k_attn<<<dim3(16,32), 256, 0, stream>>>(Qh, Kh, Vt, Y);
  k_gemm<1><<<256, 256, 0, stream>>>(Y, WpT, bp, nullptr, out, nullptr, 4096, 1024, 1024);
}